// Round 3
// baseline (763.461 us; speedup 1.0000x reference)
//
#include <hip/hip_runtime.h>
#include <math.h>

#define BB 32
#define TXX 4096
#define DD 1024
#define HD 512   // D/2

// ws layout (floats): target[B*D] @0, p1raw[B*HD] @B*D, weighted[B*D] @B*D+B*HD
//
// ROUND-3: LDS-free GEMMs. input/weighted are 128 KB -> L1/L2-resident;
// staging them in LDS (round<=2) cost barriers + occupancy. Now: 1 row/wave,
// weights hoisted to VGPRs, operand read straight from cache, no barriers.
// 4x repeat instrumentation retained: dur = fills(~580us) + 4*T_kernels.

__device__ __forceinline__ float wave_reduce64(float v) {
    v += __shfl_xor(v, 32);
    v += __shfl_xor(v, 16);
    v += __shfl_xor(v, 8);
    v += __shfl_xor(v, 4);
    v += __shfl_xor(v, 2);
    v += __shfl_xor(v, 1);
    return v;
}

// rows 0..1023 -> target[b][row] = dot(input[b,:], W_in[row,:])
// rows 1024..1535 -> p1raw[b][row-1024] = dot(input[b,:], W_p1[row-1024,:])
// 384 blocks x 256 thr; each wave owns ONE row for all 32 batches.
// 1536 waves = ~6 waves/CU; no LDS, no barriers.
__global__ __launch_bounds__(256) void k_rowdot(
    const float* __restrict__ input,   // [B,D]
    const float* __restrict__ W_in,    // [D,D]
    const float* __restrict__ W_p1,    // [HD,D]
    float* __restrict__ target,        // [B,D]
    float* __restrict__ p1raw)         // [B,HD]
{
    const int t = threadIdx.x;
    const int lane = t & 63;
    const int wv = t >> 6;
    const int row = blockIdx.x * 4 + wv;     // 0..1535

    const float* wp = (row < DD) ? (W_in + (size_t)row * DD)
                                 : (W_p1 + (size_t)(row - DD) * DD);

    // hoist the full weight row (4 chunks x float4/lane = 16 VGPRs),
    // all loads issued up-front -> streams W at full BW
    float4 wf[4];
#pragma unroll
    for (int c = 0; c < 4; ++c) wf[c] = *(const float4*)(wp + c * 256 + lane * 4);

    float acc[32];
#pragma unroll
    for (int b = 0; b < 32; ++b) acc[b] = 0.f;

#pragma unroll
    for (int c = 0; c < 4; ++c) {
#pragma unroll
        for (int b = 0; b < 32; ++b) {
            float4 x = *(const float4*)(input + (size_t)b * DD + c * 256 + lane * 4);
            acc[b] = fmaf(wf[c].x, x.x, acc[b]);
            acc[b] = fmaf(wf[c].y, x.y, acc[b]);
            acc[b] = fmaf(wf[c].z, x.z, acc[b]);
            acc[b] = fmaf(wf[c].w, x.w, acc[b]);
        }
    }

    // per-b butterfly; lane b keeps batch-b result (independent chains, ILP)
    float res = 0.f;
#pragma unroll
    for (int b = 0; b < 32; ++b) {
        float v = wave_reduce64(acc[b]);
        if (lane == b) res = v;
    }
    if (lane < 32) {
        if (row < DD) target[(size_t)lane * DD + row] = res;
        else          p1raw[(size_t)lane * HD + (row - DD)] = res;
    }
}

// One block per batch: pt -> idx -> scores -> softmax -> attn out + weighted
__global__ __launch_bounds__(256) void k_attn(
    const float* __restrict__ context, // [B,TX,D]
    const float* __restrict__ W_p2,    // [HD]
    const float* __restrict__ target,  // [B,D]
    const float* __restrict__ p1raw,   // [B,HD]
    float* __restrict__ weighted,      // [B,D]
    float* __restrict__ out_attn)      // [B,8]
{
    const int b = blockIdx.x;
    const int t = threadIdx.x;
    const int lane = t & 63;
    const int wv = t >> 6;
    __shared__ float red[4];
    __shared__ int s_idx[8];
    __shared__ float s_sc[8];

    // phase A: pt = TX * sigmoid( dot(tanh(p1), W_p2) )
    float v = tanhf(p1raw[(size_t)b * HD + t]) * W_p2[t]
            + tanhf(p1raw[(size_t)b * HD + 256 + t]) * W_p2[256 + t];
    v = wave_reduce64(v);
    if (lane == 0) red[wv] = v;
    __syncthreads();
    if (t == 0) {
        float tot = red[0] + red[1] + red[2] + red[3];
        float pt = (float)TXX * (1.0f / (1.0f + expf(-tot)));
        int bl = (int)(pt - 4.0f);   // trunc toward zero == jnp.trunc for this range
#pragma unroll
        for (int w = 0; w < 8; ++w) {
            int ix = bl + w;
            ix = ix < 0 ? 0 : (ix > TXX - 1 ? TXX - 1 : ix);
            s_idx[w] = ix;
        }
    }
    __syncthreads();

    // phase B: scores s[w] = dot(context[b, idx[w], :], target[b,:])
    const float* tgt = target + (size_t)b * DD;
    for (int w = wv; w < 8; w += 4) {
        const float* cr = context + ((size_t)b * TXX + s_idx[w]) * DD;
        float p = 0.f;
#pragma unroll
        for (int i = 0; i < 4; ++i) {
            float4 c4 = *(const float4*)(cr + i * 256 + lane * 4);
            float4 t4 = *(const float4*)(tgt + i * 256 + lane * 4);
            p += c4.x * t4.x + c4.y * t4.y + c4.z * t4.z + c4.w * t4.w;
        }
        p = wave_reduce64(p);
        if (lane == 0) s_sc[w] = p;
    }
    __syncthreads();

    // phase C: softmax (redundant per thread, cheap)
    float m = s_sc[0];
#pragma unroll
    for (int w = 1; w < 8; ++w) m = fmaxf(m, s_sc[w]);
    float e[8]; float ssum = 0.f;
#pragma unroll
    for (int w = 0; w < 8; ++w) { e[w] = expf(s_sc[w] - m); ssum += e[w]; }
    float inv = 1.0f / ssum;
    if (t < 8) out_attn[b * 8 + t] = e[t] * inv;

    // phase D: weighted[b,d] = sum_w attn[w] * context[b, idx[w], d]
    int d0 = t * 4;
    float4 acc = make_float4(0.f, 0.f, 0.f, 0.f);
#pragma unroll
    for (int w = 0; w < 8; ++w) {
        float aw = e[w] * inv;
        float4 c4 = *(const float4*)(context + ((size_t)b * TXX + s_idx[w]) * DD + d0);
        acc.x = fmaf(aw, c4.x, acc.x);
        acc.y = fmaf(aw, c4.y, acc.y);
        acc.z = fmaf(aw, c4.z, acc.z);
        acc.w = fmaf(aw, c4.w, acc.w);
    }
    *(float4*)(weighted + (size_t)b * DD + d0) = acc;
}

// h_tilde[b][row] = tanh( dot([weighted|input][b,:], W_out[row,:]) ), K=2048
// 256 blocks x 256 thr; 1 row/wave; LDS-free (weighted+input are L2-hot).
__global__ __launch_bounds__(256) void k_out(
    const float* __restrict__ input,    // [B,D]
    const float* __restrict__ W_out,    // [D, 2D]
    const float* __restrict__ weighted, // [B,D]
    float* __restrict__ out)            // [B,D]
{
    const int t = threadIdx.x;
    const int lane = t & 63;
    const int wv = t >> 6;
    const int row = blockIdx.x * 4 + wv;     // 0..1023

    const float* wp = W_out + (size_t)row * 2048;

    // full weight row hoisted: 8 chunks x float4 = 32 VGPRs, issued up-front
    float4 wf[8];
#pragma unroll
    for (int c = 0; c < 8; ++c) wf[c] = *(const float4*)(wp + c * 256 + lane * 4);

    float acc[32];
#pragma unroll
    for (int b = 0; b < 32; ++b) acc[b] = 0.f;

#pragma unroll
    for (int c = 0; c < 8; ++c) {
        const float* src = (c < 4) ? (weighted + c * 256) : (input + (c - 4) * 256);
#pragma unroll
        for (int b = 0; b < 32; ++b) {
            float4 x = *(const float4*)(src + (size_t)b * DD + lane * 4);
            acc[b] = fmaf(wf[c].x, x.x, acc[b]);
            acc[b] = fmaf(wf[c].y, x.y, acc[b]);
            acc[b] = fmaf(wf[c].z, x.z, acc[b]);
            acc[b] = fmaf(wf[c].w, x.w, acc[b]);
        }
    }

    float res = 0.f;
#pragma unroll
    for (int b = 0; b < 32; ++b) {
        float v = wave_reduce64(acc[b]);
        if (lane == b) res = v;
    }
    if (lane < 32) out[(size_t)lane * DD + row] = tanhf(res);
}

extern "C" void kernel_launch(void* const* d_in, const int* in_sizes, int n_in,
                              void* d_out, int out_size, void* d_ws, size_t ws_size,
                              hipStream_t stream) {
    const float* input   = (const float*)d_in[0];
    const float* context = (const float*)d_in[1];
    const float* W_in    = (const float*)d_in[2];
    const float* W_out   = (const float*)d_in[3];
    const float* W_p1    = (const float*)d_in[4];
    const float* W_p2    = (const float*)d_in[5];
    float* out = (float*)d_out;
    float* ws  = (float*)d_ws;

    float* target   = ws;                    // B*D
    float* p1raw    = ws + BB * DD;          // B*HD
    float* weighted = ws + BB * DD + BB * HD;

    // INSTRUMENTATION (one more round): repeat the idempotent sequence 4x.
    // T_kernels = (dur_us - ~580us fills) / 4. Outputs bit-identical to 1x.
    for (int rep = 0; rep < 4; ++rep) {
        k_rowdot<<<384, 256, 0, stream>>>(input, W_in, W_p1, target, p1raw);
        k_attn<<<32, 256, 0, stream>>>(context, W_p2, target, p1raw, weighted, out + BB * DD);
        k_out<<<256, 256, 0, stream>>>(input, W_out, weighted, out);
    }
}

// Round 4
// 604.733 us; speedup vs baseline: 1.2625x; 1.2625x over previous
//
#include <hip/hip_runtime.h>
#include <math.h>

#define BB 32
#define TXX 4096
#define DD 1024
#define HD 512   // D/2

// ws layout (floats): target[B*D] @0, p1raw[B*HD] @B*D, weighted[B*D] @B*D+B*HD
//
// ROUND-4: pure revert to the round-1 best-known kernel (single-shot,
// LDS double-buffered GEMMs, T_kernels ~= 28us measured via the 4x amplifier).
// Round-3's LDS-free variant regressed T to ~45us: at 1-1.5 blocks/CU the
// vector-cache path exposes L2/HBM load latency that the 8-wave LDS-broadcast
// structure hides (G1: occupancy first; common-mistake-7 does NOT apply when
// dropping LDS also drops TLP).

__device__ __forceinline__ float wave_reduce64(float v) {
    v += __shfl_xor(v, 32);
    v += __shfl_xor(v, 16);
    v += __shfl_xor(v, 8);
    v += __shfl_xor(v, 4);
    v += __shfl_xor(v, 2);
    v += __shfl_xor(v, 1);
    return v;
}

// Fused skinny GEMM: rows 0..1023 -> target[b][r] = dot(input[b,:], W_in[r,:])
//                    rows 1024..1535 -> p1raw[b][r-1024] = dot(input[b,:], W_p1[r-1024,:])
// Each wave handles 2 rows for all 32 batches; lane covers k = c*256 + lane*4.
// Double-buffered LDS + issue-early/write-late staging: one barrier per chunk.
__global__ __launch_bounds__(256) void k_rowdot(
    const float* __restrict__ input,   // [B,D]
    const float* __restrict__ W_in,    // [D,D]
    const float* __restrict__ W_p1,    // [HD,D]
    float* __restrict__ target,        // [B,D]
    float* __restrict__ p1raw)         // [B,HD]
{
    __shared__ __align__(16) float s_in[2][32 * 256];
    const int t = threadIdx.x;
    const int lane = t & 63;
    const int wv = t >> 6;
    const int row0 = blockIdx.x * 8 + wv * 2;
    const int row1 = row0 + 1;

    const float* w0p = (row0 < DD) ? (W_in + (size_t)row0 * DD) : (W_p1 + (size_t)(row0 - DD) * DD);
    const float* w1p = (row1 < DD) ? (W_in + (size_t)row1 * DD) : (W_p1 + (size_t)(row1 - DD) * DD);

    // hoist all weight fragments (4 chunks x 2 rows = 32 VGPRs)
    float4 wf0[4], wf1[4];
#pragma unroll
    for (int c = 0; c < 4; ++c) {
        wf0[c] = *(const float4*)(w0p + c * 256 + lane * 4);
        wf1[c] = *(const float4*)(w1p + c * 256 + lane * 4);
    }

    float acc0[32], acc1[32];
#pragma unroll
    for (int b = 0; b < 32; ++b) { acc0[b] = 0.f; acc1[b] = 0.f; }

    // stage chunk 0 into buf 0
    {
        float4 st[8];
#pragma unroll
        for (int i = 0; i < 8; ++i) {
            int f = t + i * 256;           // float4 index in [0,2048)
            int b = f >> 6;
            int kl4 = f & 63;
            st[i] = *(const float4*)(input + (size_t)b * DD + kl4 * 4);
        }
#pragma unroll
        for (int i = 0; i < 8; ++i) ((float4*)s_in[0])[t + i * 256] = st[i];
    }
    __syncthreads();

#pragma unroll
    for (int c = 0; c < 4; ++c) {
        // issue next chunk's global loads early (latency hides under FMAs)
        float4 st[8];
        if (c < 3) {
#pragma unroll
            for (int i = 0; i < 8; ++i) {
                int f = t + i * 256;
                int b = f >> 6;
                int kl4 = f & 63;
                st[i] = *(const float4*)(input + (size_t)b * DD + (c + 1) * 256 + kl4 * 4);
            }
        }
        const float4* xb = (const float4*)s_in[c & 1];
        const float4 w0 = wf0[c], w1 = wf1[c];
#pragma unroll
        for (int b = 0; b < 32; ++b) {
            float4 x = xb[b * 64 + lane];
            acc0[b] = fmaf(w0.x, x.x, acc0[b]);
            acc0[b] = fmaf(w0.y, x.y, acc0[b]);
            acc0[b] = fmaf(w0.z, x.z, acc0[b]);
            acc0[b] = fmaf(w0.w, x.w, acc0[b]);
            acc1[b] = fmaf(w1.x, x.x, acc1[b]);
            acc1[b] = fmaf(w1.y, x.y, acc1[b]);
            acc1[b] = fmaf(w1.z, x.z, acc1[b]);
            acc1[b] = fmaf(w1.w, x.w, acc1[b]);
        }
        if (c < 3) {
            // write-late into the other buffer, then single barrier
#pragma unroll
            for (int i = 0; i < 8; ++i) ((float4*)s_in[(c + 1) & 1])[t + i * 256] = st[i];
            __syncthreads();
        }
    }

    // cross-lane reduce: lanes<32 end with row0 sum for b=lane, lanes>=32 row1 for b=lane-32
    float res = 0.f;
#pragma unroll
    for (int b = 0; b < 32; ++b) {
        float s0 = acc0[b] + __shfl_xor(acc0[b], 32);
        float s1 = acc1[b] + __shfl_xor(acc1[b], 32);
        float v = (lane < 32) ? s0 : s1;
        v += __shfl_xor(v, 16);
        v += __shfl_xor(v, 8);
        v += __shfl_xor(v, 4);
        v += __shfl_xor(v, 2);
        v += __shfl_xor(v, 1);
        if ((lane & 31) == b) res = v;
    }
    int r = (lane < 32) ? row0 : row1;
    int b = lane & 31;
    if (r < DD) target[(size_t)b * DD + r] = res;
    else        p1raw[(size_t)b * HD + (r - DD)] = res;
}

// One block per batch: pt -> idx -> scores -> softmax -> attn out + weighted
__global__ __launch_bounds__(256) void k_attn(
    const float* __restrict__ context, // [B,TX,D]
    const float* __restrict__ W_p2,    // [HD]
    const float* __restrict__ target,  // [B,D]
    const float* __restrict__ p1raw,   // [B,HD]
    float* __restrict__ weighted,      // [B,D]
    float* __restrict__ out_attn)      // [B,8]
{
    const int b = blockIdx.x;
    const int t = threadIdx.x;
    const int lane = t & 63;
    const int wv = t >> 6;
    __shared__ float red[4];
    __shared__ int s_idx[8];
    __shared__ float s_sc[8];

    // phase A: pt = TX * sigmoid( dot(tanh(p1), W_p2) )
    float v = tanhf(p1raw[(size_t)b * HD + t]) * W_p2[t]
            + tanhf(p1raw[(size_t)b * HD + 256 + t]) * W_p2[256 + t];
    v = wave_reduce64(v);
    if (lane == 0) red[wv] = v;
    __syncthreads();
    if (t == 0) {
        float tot = red[0] + red[1] + red[2] + red[3];
        float pt = (float)TXX * (1.0f / (1.0f + expf(-tot)));
        int bl = (int)(pt - 4.0f);   // trunc toward zero == jnp.trunc for this range
#pragma unroll
        for (int w = 0; w < 8; ++w) {
            int ix = bl + w;
            ix = ix < 0 ? 0 : (ix > TXX - 1 ? TXX - 1 : ix);
            s_idx[w] = ix;
        }
    }
    __syncthreads();

    // phase B: scores s[w] = dot(context[b, idx[w], :], target[b,:])
    const float* tgt = target + (size_t)b * DD;
    for (int w = wv; w < 8; w += 4) {
        const float* cr = context + ((size_t)b * TXX + s_idx[w]) * DD;
        float p = 0.f;
#pragma unroll
        for (int i = 0; i < 4; ++i) {
            float4 c4 = *(const float4*)(cr + i * 256 + lane * 4);
            float4 t4 = *(const float4*)(tgt + i * 256 + lane * 4);
            p += c4.x * t4.x + c4.y * t4.y + c4.z * t4.z + c4.w * t4.w;
        }
        p = wave_reduce64(p);
        if (lane == 0) s_sc[w] = p;
    }
    __syncthreads();

    // phase C: softmax (redundant per thread, cheap)
    float m = s_sc[0];
#pragma unroll
    for (int w = 1; w < 8; ++w) m = fmaxf(m, s_sc[w]);
    float e[8]; float ssum = 0.f;
#pragma unroll
    for (int w = 0; w < 8; ++w) { e[w] = expf(s_sc[w] - m); ssum += e[w]; }
    float inv = 1.0f / ssum;
    if (t < 8) out_attn[b * 8 + t] = e[t] * inv;

    // phase D: weighted[b,d] = sum_w attn[w] * context[b, idx[w], d]
    int d0 = t * 4;
    float4 acc = make_float4(0.f, 0.f, 0.f, 0.f);
#pragma unroll
    for (int w = 0; w < 8; ++w) {
        float aw = e[w] * inv;
        float4 c4 = *(const float4*)(context + ((size_t)b * TXX + s_idx[w]) * DD + d0);
        acc.x = fmaf(aw, c4.x, acc.x);
        acc.y = fmaf(aw, c4.y, acc.y);
        acc.z = fmaf(aw, c4.z, acc.z);
        acc.w = fmaf(aw, c4.w, acc.w);
    }
    *(float4*)(weighted + (size_t)b * DD + d0) = acc;
}

// h_tilde[b][r] = tanh( dot([weighted|input][b,:], W_out[r,:]) ), K=2048
// Same double-buffer + issue-early/write-late structure as k_rowdot.
__global__ __launch_bounds__(256) void k_out(
    const float* __restrict__ input,    // [B,D]
    const float* __restrict__ W_out,    // [D, 2D]
    const float* __restrict__ weighted, // [B,D]
    float* __restrict__ out)            // [B,D]
{
    __shared__ __align__(16) float s_in[2][32 * 256];
    const int t = threadIdx.x;
    const int lane = t & 63;
    const int wv = t >> 6;
    const int row0 = blockIdx.x * 8 + wv * 2;
    const int row1 = row0 + 1;
    const float* w0p = W_out + (size_t)row0 * 2048;
    const float* w1p = W_out + (size_t)row1 * 2048;

    float acc0[32], acc1[32];
#pragma unroll
    for (int b = 0; b < 32; ++b) { acc0[b] = 0.f; acc1[b] = 0.f; }

    // stage chunk 0 (weighted[:, 0:256]) into buf 0
    {
        float4 st[8];
#pragma unroll
        for (int i = 0; i < 8; ++i) {
            int f = t + i * 256;
            int b = f >> 6;
            int kl4 = f & 63;
            st[i] = *(const float4*)(weighted + (size_t)b * DD + kl4 * 4);
        }
#pragma unroll
        for (int i = 0; i < 8; ++i) ((float4*)s_in[0])[t + i * 256] = st[i];
    }
    __syncthreads();

#pragma unroll
    for (int c = 0; c < 8; ++c) {
        float4 st[8];
        if (c < 7) {
            const int cn = c + 1;
            const float* src = (cn < 4) ? (weighted + cn * 256) : (input + (cn - 4) * 256);
#pragma unroll
            for (int i = 0; i < 8; ++i) {
                int f = t + i * 256;
                int b = f >> 6;
                int kl4 = f & 63;
                st[i] = *(const float4*)(src + (size_t)b * DD + kl4 * 4);
            }
        }
        const float4 w0 = *(const float4*)(w0p + c * 256 + lane * 4);
        const float4 w1 = *(const float4*)(w1p + c * 256 + lane * 4);
        const float4* xb = (const float4*)s_in[c & 1];
#pragma unroll
        for (int b = 0; b < 32; ++b) {
            float4 x = xb[b * 64 + lane];
            acc0[b] = fmaf(w0.x, x.x, acc0[b]);
            acc0[b] = fmaf(w0.y, x.y, acc0[b]);
            acc0[b] = fmaf(w0.z, x.z, acc0[b]);
            acc0[b] = fmaf(w0.w, x.w, acc0[b]);
            acc1[b] = fmaf(w1.x, x.x, acc1[b]);
            acc1[b] = fmaf(w1.y, x.y, acc1[b]);
            acc1[b] = fmaf(w1.z, x.z, acc1[b]);
            acc1[b] = fmaf(w1.w, x.w, acc1[b]);
        }
        if (c < 7) {
#pragma unroll
            for (int i = 0; i < 8; ++i) ((float4*)s_in[(c + 1) & 1])[t + i * 256] = st[i];
            __syncthreads();
        }
    }

    float res = 0.f;
#pragma unroll
    for (int b = 0; b < 32; ++b) {
        float s0 = acc0[b] + __shfl_xor(acc0[b], 32);
        float s1 = acc1[b] + __shfl_xor(acc1[b], 32);
        float v = (lane < 32) ? s0 : s1;
        v += __shfl_xor(v, 16);
        v += __shfl_xor(v, 8);
        v += __shfl_xor(v, 4);
        v += __shfl_xor(v, 2);
        v += __shfl_xor(v, 1);
        if ((lane & 31) == b) res = v;
    }
    int r = (lane < 32) ? row0 : row1;
    int b = lane & 31;
    out[(size_t)b * DD + r] = tanhf(res);
}

extern "C" void kernel_launch(void* const* d_in, const int* in_sizes, int n_in,
                              void* d_out, int out_size, void* d_ws, size_t ws_size,
                              hipStream_t stream) {
    const float* input   = (const float*)d_in[0];
    const float* context = (const float*)d_in[1];
    const float* W_in    = (const float*)d_in[2];
    const float* W_out   = (const float*)d_in[3];
    const float* W_p1    = (const float*)d_in[4];
    const float* W_p2    = (const float*)d_in[5];
    float* out = (float*)d_out;
    float* ws  = (float*)d_ws;

    float* target   = ws;                    // B*D
    float* p1raw    = ws + BB * DD;          // B*HD
    float* weighted = ws + BB * DD + BB * HD;

    k_rowdot<<<192, 256, 0, stream>>>(input, W_in, W_p1, target, p1raw);
    k_attn<<<32, 256, 0, stream>>>(context, W_p2, target, p1raw, weighted, out + BB * DD);
    k_out<<<128, 256, 0, stream>>>(input, W_out, weighted, out);
}